// Round 8
// baseline (389.781 us; speedup 1.0000x reference)
//
#include <hip/hip_runtime.h>
#include <math.h>

#define NATOMS  512
#define MROWS   64
#define BATCH   65536
#define BT      4           // batch columns per block (1 per wave)
#define NSPARSE 5
#define DEPSF   1e-6f

typedef float v2f __attribute__((ext_vector_type(2)));

// ---------------------------------------------------------------------------
// prep: gram = D^T D (f64 accumulate -> f32). 1024 blocks x 256 threads.
// ---------------------------------------------------------------------------
__global__ void ksvd_prep(const float* __restrict__ D,
                          float* __restrict__ gram) {
  const int idx = blockIdx.x * 256 + threadIdx.x;     // 0 .. 512*512-1
  const int i = idx >> 9;
  const int j = idx & (NATOMS - 1);
  double acc = 0.0;
#pragma unroll 8
  for (int m = 0; m < MROWS; ++m)
    acc += (double)D[m * NATOMS + i] * (double)D[m * NATOMS + j];
  gram[idx] = (float)acc;
}

// ---------------------------------------------------------------------------
// wave64 max-reduce on the VALU via DPP (no LDS ops, no lgkmcnt waits).
// bound_ctrl=true feeds 0 for shifted-out lanes: harmless, keys are >= 0.
// ---------------------------------------------------------------------------
__device__ __forceinline__ float wave_max_nonneg(float x) {
  int v = __builtin_bit_cast(int, x);
#define DPP_MAX_STEP(ctrl)                                                   \
  {                                                                          \
    const int t = __builtin_amdgcn_update_dpp(0, v, (ctrl), 0xf, 0xf, true); \
    v = __builtin_bit_cast(                                                  \
        int, fmaxf(__builtin_bit_cast(float, v), __builtin_bit_cast(float, t))); \
  }
  DPP_MAX_STEP(0x111)   // row_shr:1
  DPP_MAX_STEP(0x112)   // row_shr:2
  DPP_MAX_STEP(0x114)   // row_shr:4
  DPP_MAX_STEP(0x118)   // row_shr:8
  DPP_MAX_STEP(0x142)   // row_bcast15
  DPP_MAX_STEP(0x143)   // row_bcast31
#undef DPP_MAX_STEP
  return __builtin_bit_cast(float, __builtin_amdgcn_readlane(v, 63));
}

// ---------------------------------------------------------------------------
// main: block = 4 waves = 4 batch columns (one per wave).
// LDS is a UNION of the phase-1 X staging buffer and the dtx transpose
// buffer (xs4 is dead after the m-loop; a barrier separates last read from
// first overwrite) -> static LDS = 8192 B, targeting 8 blocks/CU even under
// a 64 KB occupancy pool (the working theory for the 4-5 block plateau).
// Numerics bit-identical to round 7.
// ---------------------------------------------------------------------------
__global__ __launch_bounds__(256, 8) void ksvd_main(
    const float* __restrict__ X, const float* __restrict__ D,
    const float* __restrict__ gram, float* __restrict__ out) {
  __shared__ union {
    float4 xs4[MROWS][BT / 2];       // 2 KB: {x2p,x2p,x2p+1,x2p+1} per m
    float  dtxT[BT][NATOMS];         // 8 KB: dtx transposed per column
  } sh;                              // -> 8192 B total

  const int t    = threadIdx.x;
  const int lane = t & 63;
  const int wave = t >> 6;                      // 0..3
  const int b0   = blockIdx.x * BT;

  // ---- stage X tile (64 m x 4 c) duplicated: xs4[m][p]={x2p,x2p,x2p+1,x2p+1}
  if (t < MROWS * 2) {
    const int m = t >> 1, p = t & 1;
    const float x0 = X[(size_t)m * BATCH + b0 + 2 * p];
    const float x1 = X[(size_t)m * BATCH + b0 + 2 * p + 1];
    float4 v; v.x = x0; v.y = x0; v.z = x1; v.w = x1;
    sh.xs4[m][p] = v;
  }
  __syncthreads();

  // ---- phase 1: lane owns atom pair (a0, a0+1), a0 = 128*wave + 2*lane
  const int a0 = wave * 128 + 2 * lane;
  v2f accA[BT], accB[BT];
#pragma unroll
  for (int c = 0; c < BT; ++c) {
    accA[c].x = 0.f; accA[c].y = 0.f;
    accB[c].x = 0.f; accB[c].y = 0.f;
  }

#pragma unroll 4
  for (int m = 0; m < MROWS; m += 2) {
    const v2f dA = *reinterpret_cast<const v2f*>(&D[m * NATOMS + a0]);
    const v2f dB = *reinterpret_cast<const v2f*>(&D[(m + 1) * NATOMS + a0]);
    const float4 xa0 = sh.xs4[m][0];
    const float4 xa1 = sh.xs4[m][1];
    const float4 xb0 = sh.xs4[m + 1][0];
    const float4 xb1 = sh.xs4[m + 1][1];
    v2f xv;
    xv.x = xa0.x; xv.y = xa0.y; accA[0] = __builtin_elementwise_fma(dA, xv, accA[0]);
    xv.x = xa0.z; xv.y = xa0.w; accA[1] = __builtin_elementwise_fma(dA, xv, accA[1]);
    xv.x = xa1.x; xv.y = xa1.y; accA[2] = __builtin_elementwise_fma(dA, xv, accA[2]);
    xv.x = xa1.z; xv.y = xa1.w; accA[3] = __builtin_elementwise_fma(dA, xv, accA[3]);
    xv.x = xb0.x; xv.y = xb0.y; accB[0] = __builtin_elementwise_fma(dB, xv, accB[0]);
    xv.x = xb0.z; xv.y = xb0.w; accB[1] = __builtin_elementwise_fma(dB, xv, accB[1]);
    xv.x = xb1.x; xv.y = xb1.y; accB[2] = __builtin_elementwise_fma(dB, xv, accB[2]);
    xv.x = xb1.z; xv.y = xb1.w; accB[3] = __builtin_elementwise_fma(dB, xv, accB[3]);
  }
  __syncthreads();   // all xs4 reads complete before dtxT overwrites the union

#pragma unroll
  for (int c = 0; c < BT; ++c) {
    const v2f s = accA[c] + accB[c];
    *reinterpret_cast<v2f*>(&sh.dtxT[c][a0]) = s;
  }
  __syncthreads();

  // ---- phase 2: this wave's column; lane owns 8 consecutive atoms 8l..8l+7
  const int cglob = b0 + wave;
  float dtxr[8];
  {
    const float4 f0 = *reinterpret_cast<const float4*>(&sh.dtxT[wave][8 * lane]);
    const float4 f1 = *reinterpret_cast<const float4*>(&sh.dtxT[wave][8 * lane + 4]);
    dtxr[0] = f0.x; dtxr[1] = f0.y; dtxr[2] = f0.z; dtxr[3] = f0.w;
    dtxr[4] = f1.x; dtxr[5] = f1.y; dtxr[6] = f1.z; dtxr[7] = f1.w;
  }

  int   idxs[NSPARSE];
  float rhsf[NSPARSE];
  float gc[NSPARSE - 1][8];                 // cached gram columns (f32)
  float L[NSPARSE][NSPARSE];                // lower-tri Cholesky (static idx)
  float inv_d[NSPARSE];
  float y[NSPARSE];
  float sol[NSPARSE];

#pragma unroll
  for (int k = 0; k < NSPARSE; ++k) {
    // corr = dtx - sum_s sol[s]*gc_s (f32); f32-key argmax, first-max ties
    float bv = -1.0f;
    int   bn = 0;
#pragma unroll
    for (int jj = 0; jj < 8; ++jj) {
      float cv = dtxr[jj];
#pragma unroll
      for (int s = 0; s < k; ++s) cv -= sol[s] * gc[s][jj];
      const float av = fabsf(cv);
      if (av > bv) { bv = av; bn = 8 * lane + jj; }   // strict >: first-max
    }
    // wave max on the VALU (DPP), then owner = lowest lane holding the max
    const float wmax = wave_max_nonneg(bv);
    const unsigned long long own = __ballot(bv == wmax);
    const int owner = __ffsll((long long)own) - 1;    // lowest lane: first-max
    const int idx = __builtin_amdgcn_readlane(bn, owner);  // uniform (SGPR)
    idxs[k] = idx;

    // gram column for future corr updates (vector, L2-resident)
    if (k < NSPARSE - 1) {
      const float4 g0 = *reinterpret_cast<const float4*>(
          &gram[(size_t)idx * NATOMS + 8 * lane]);
      const float4 g1 = *reinterpret_cast<const float4*>(
          &gram[(size_t)idx * NATOMS + 8 * lane + 4]);
      gc[k][0] = g0.x; gc[k][1] = g0.y; gc[k][2] = g0.z; gc[k][3] = g0.w;
      gc[k][4] = g1.x; gc[k][5] = g1.y; gc[k][6] = g1.z; gc[k][7] = g1.w;
    }

    // rhs: one uniform LDS read (broadcast)
    rhsf[k] = sh.dtxT[wave][idx];

    // Gram row k entries: uniform (scalar) loads
    float arowf[NSPARSE];
#pragma unroll
    for (int j = 0; j < k; ++j)
      arowf[j] = gram[(size_t)idx * NATOMS + idxs[j]];
    const float gdiag = gram[(size_t)idx * NATOMS + idx];

    // incremental Cholesky row k of (G_active + eps*I), rsqrtf-based
    float ss = gdiag + DEPSF;
#pragma unroll
    for (int j = 0; j < k; ++j) {
      float w = arowf[j];
#pragma unroll
      for (int tt = 0; tt < j; ++tt) w -= L[k][tt] * L[j][tt];
      w *= inv_d[j];
      L[k][j] = w;
      ss -= w * w;
    }
    const float inv = rsqrtf(ss);
    L[k][k]  = ss * inv;                    // = sqrt(ss)
    inv_d[k] = inv;

    // forward substitution: only y[k] is new (y[0..k-1] unchanged)
    {
      float s2 = rhsf[k];
#pragma unroll
      for (int j = 0; j < k; ++j) s2 -= L[k][j] * y[j];
      y[k] = s2 * inv;
    }
    // backward substitution (full, sol changes every round)
#pragma unroll
    for (int i = k; i >= 0; --i) {
      float s2 = y[i];
#pragma unroll
      for (int j = i + 1; j <= k; ++j) s2 -= L[j][i] * sol[j];
      sol[i] = s2 * inv_d[i];
    }
  }

  // ---- epilogue: scatter the 5 coefficients (out pre-zeroed by memset)
  if (lane == 0) {
#pragma unroll
    for (int s = 0; s < NSPARSE; ++s)
      out[(size_t)idxs[s] * BATCH + cglob] = sol[s];
  }
}

// ---------------------------------------------------------------------------
extern "C" void kernel_launch(void* const* d_in, const int* in_sizes, int n_in,
                              void* d_out, int out_size, void* d_ws,
                              size_t ws_size, hipStream_t stream) {
  (void)in_sizes; (void)n_in; (void)out_size; (void)ws_size;
  const float* X = (const float*)d_in[0];   // (64, 65536)
  const float* D = (const float*)d_in[1];   // (64, 512)
  float* out = (float*)d_out;               // (512, 65536)
  float* gram = (float*)d_ws;               // 1 MB scratch

  ksvd_prep<<<(NATOMS * NATOMS) / 256, 256, 0, stream>>>(D, gram);
  hipMemsetAsync(out, 0, (size_t)NATOMS * BATCH * sizeof(float), stream);
  ksvd_main<<<BATCH / BT, 256, 0, stream>>>(X, D, gram, out);
}

// Round 9
// 176.768 us; speedup vs baseline: 2.2050x; 2.2050x over previous
//
#include <hip/hip_runtime.h>
#include <math.h>

#define NATOMS  512
#define MROWS   64
#define BATCH   65536
#define BT      4           // batch columns per block (1 per wave)
#define NSPARSE 5
#define DEPSF   1e-6f

typedef float v2f __attribute__((ext_vector_type(2)));

// ---------------------------------------------------------------------------
// prep: gram = D^T D (f64 accumulate -> f32). 1024 blocks x 256 threads.
// ---------------------------------------------------------------------------
__global__ void ksvd_prep(const float* __restrict__ D,
                          float* __restrict__ gram) {
  const int idx = blockIdx.x * 256 + threadIdx.x;     // 0 .. 512*512-1
  const int i = idx >> 9;
  const int j = idx & (NATOMS - 1);
  double acc = 0.0;
#pragma unroll 8
  for (int m = 0; m < MROWS; ++m)
    acc += (double)D[m * NATOMS + i] * (double)D[m * NATOMS + j];
  gram[idx] = (float)acc;
}

// ---------------------------------------------------------------------------
// wave64 max-reduce on the VALU via DPP (no LDS ops, no lgkmcnt waits).
// bound_ctrl=true feeds 0 for shifted-out lanes: harmless, keys are >= 0.
// ---------------------------------------------------------------------------
__device__ __forceinline__ float wave_max_nonneg(float x) {
  int v = __builtin_bit_cast(int, x);
#define DPP_MAX_STEP(ctrl)                                                   \
  {                                                                          \
    const int t = __builtin_amdgcn_update_dpp(0, v, (ctrl), 0xf, 0xf, true); \
    v = __builtin_bit_cast(                                                  \
        int, fmaxf(__builtin_bit_cast(float, v), __builtin_bit_cast(float, t))); \
  }
  DPP_MAX_STEP(0x111)   // row_shr:1
  DPP_MAX_STEP(0x112)   // row_shr:2
  DPP_MAX_STEP(0x114)   // row_shr:4
  DPP_MAX_STEP(0x118)   // row_shr:8
  DPP_MAX_STEP(0x142)   // row_bcast15
  DPP_MAX_STEP(0x143)   // row_bcast31
#undef DPP_MAX_STEP
  return __builtin_bit_cast(float, __builtin_amdgcn_readlane(v, 63));
}

// ---------------------------------------------------------------------------
// main: block = 4 waves = 4 batch columns (one per wave).
// LDS = union of phase-1 X staging and the dtx transpose buffer -> 8192 B
// -> 8 blocks/CU (validated in round 8: occupancy 89.6%).
// __launch_bounds__ kept at 4 waves/EU: round 8 showed that forcing 8
// clamps VGPR to 32 and spills phase-2 state to scratch (724 MB of spill
// writes). At the natural VGPR=48 the register pool allows 8 waves/SIMD
// anyway, so the bound only needs to not-constrain the allocator.
// Numerics bit-identical to rounds 6-8.
// ---------------------------------------------------------------------------
__global__ __launch_bounds__(256, 4) void ksvd_main(
    const float* __restrict__ X, const float* __restrict__ D,
    const float* __restrict__ gram, float* __restrict__ out) {
  __shared__ union {
    float4 xs4[MROWS][BT / 2];       // 2 KB: {x2p,x2p,x2p+1,x2p+1} per m
    float  dtxT[BT][NATOMS];         // 8 KB: dtx transposed per column
  } sh;                              // -> 8192 B total

  const int t    = threadIdx.x;
  const int lane = t & 63;
  const int wave = t >> 6;                      // 0..3
  const int b0   = blockIdx.x * BT;

  // ---- stage X tile (64 m x 4 c) duplicated: xs4[m][p]={x2p,x2p,x2p+1,x2p+1}
  if (t < MROWS * 2) {
    const int m = t >> 1, p = t & 1;
    const float x0 = X[(size_t)m * BATCH + b0 + 2 * p];
    const float x1 = X[(size_t)m * BATCH + b0 + 2 * p + 1];
    float4 v; v.x = x0; v.y = x0; v.z = x1; v.w = x1;
    sh.xs4[m][p] = v;
  }
  __syncthreads();

  // ---- phase 1: lane owns atom pair (a0, a0+1), a0 = 128*wave + 2*lane
  const int a0 = wave * 128 + 2 * lane;
  v2f accA[BT], accB[BT];
#pragma unroll
  for (int c = 0; c < BT; ++c) {
    accA[c].x = 0.f; accA[c].y = 0.f;
    accB[c].x = 0.f; accB[c].y = 0.f;
  }

#pragma unroll 4
  for (int m = 0; m < MROWS; m += 2) {
    const v2f dA = *reinterpret_cast<const v2f*>(&D[m * NATOMS + a0]);
    const v2f dB = *reinterpret_cast<const v2f*>(&D[(m + 1) * NATOMS + a0]);
    const float4 xa0 = sh.xs4[m][0];
    const float4 xa1 = sh.xs4[m][1];
    const float4 xb0 = sh.xs4[m + 1][0];
    const float4 xb1 = sh.xs4[m + 1][1];
    v2f xv;
    xv.x = xa0.x; xv.y = xa0.y; accA[0] = __builtin_elementwise_fma(dA, xv, accA[0]);
    xv.x = xa0.z; xv.y = xa0.w; accA[1] = __builtin_elementwise_fma(dA, xv, accA[1]);
    xv.x = xa1.x; xv.y = xa1.y; accA[2] = __builtin_elementwise_fma(dA, xv, accA[2]);
    xv.x = xa1.z; xv.y = xa1.w; accA[3] = __builtin_elementwise_fma(dA, xv, accA[3]);
    xv.x = xb0.x; xv.y = xb0.y; accB[0] = __builtin_elementwise_fma(dB, xv, accB[0]);
    xv.x = xb0.z; xv.y = xb0.w; accB[1] = __builtin_elementwise_fma(dB, xv, accB[1]);
    xv.x = xb1.x; xv.y = xb1.y; accB[2] = __builtin_elementwise_fma(dB, xv, accB[2]);
    xv.x = xb1.z; xv.y = xb1.w; accB[3] = __builtin_elementwise_fma(dB, xv, accB[3]);
  }
  __syncthreads();   // all xs4 reads complete before dtxT overwrites the union

#pragma unroll
  for (int c = 0; c < BT; ++c) {
    const v2f s = accA[c] + accB[c];
    *reinterpret_cast<v2f*>(&sh.dtxT[c][a0]) = s;
  }
  __syncthreads();

  // ---- phase 2: this wave's column; lane owns 8 consecutive atoms 8l..8l+7
  const int cglob = b0 + wave;
  float dtxr[8];
  {
    const float4 f0 = *reinterpret_cast<const float4*>(&sh.dtxT[wave][8 * lane]);
    const float4 f1 = *reinterpret_cast<const float4*>(&sh.dtxT[wave][8 * lane + 4]);
    dtxr[0] = f0.x; dtxr[1] = f0.y; dtxr[2] = f0.z; dtxr[3] = f0.w;
    dtxr[4] = f1.x; dtxr[5] = f1.y; dtxr[6] = f1.z; dtxr[7] = f1.w;
  }

  int   idxs[NSPARSE];
  float rhsf[NSPARSE];
  float gc[NSPARSE - 1][8];                 // cached gram columns (f32)
  float L[NSPARSE][NSPARSE];                // lower-tri Cholesky (static idx)
  float inv_d[NSPARSE];
  float y[NSPARSE];
  float sol[NSPARSE];

#pragma unroll
  for (int k = 0; k < NSPARSE; ++k) {
    // corr = dtx - sum_s sol[s]*gc_s (f32); f32-key argmax, first-max ties
    float bv = -1.0f;
    int   bn = 0;
#pragma unroll
    for (int jj = 0; jj < 8; ++jj) {
      float cv = dtxr[jj];
#pragma unroll
      for (int s = 0; s < k; ++s) cv -= sol[s] * gc[s][jj];
      const float av = fabsf(cv);
      if (av > bv) { bv = av; bn = 8 * lane + jj; }   // strict >: first-max
    }
    // wave max on the VALU (DPP), then owner = lowest lane holding the max
    const float wmax = wave_max_nonneg(bv);
    const unsigned long long own = __ballot(bv == wmax);
    const int owner = __ffsll((long long)own) - 1;    // lowest lane: first-max
    const int idx = __builtin_amdgcn_readlane(bn, owner);  // uniform (SGPR)
    idxs[k] = idx;

    // gram column for future corr updates (vector, L2-resident)
    if (k < NSPARSE - 1) {
      const float4 g0 = *reinterpret_cast<const float4*>(
          &gram[(size_t)idx * NATOMS + 8 * lane]);
      const float4 g1 = *reinterpret_cast<const float4*>(
          &gram[(size_t)idx * NATOMS + 8 * lane + 4]);
      gc[k][0] = g0.x; gc[k][1] = g0.y; gc[k][2] = g0.z; gc[k][3] = g0.w;
      gc[k][4] = g1.x; gc[k][5] = g1.y; gc[k][6] = g1.z; gc[k][7] = g1.w;
    }

    // rhs: one uniform LDS read (broadcast)
    rhsf[k] = sh.dtxT[wave][idx];

    // Gram row k entries: uniform (scalar) loads
    float arowf[NSPARSE];
#pragma unroll
    for (int j = 0; j < k; ++j)
      arowf[j] = gram[(size_t)idx * NATOMS + idxs[j]];
    const float gdiag = gram[(size_t)idx * NATOMS + idx];

    // incremental Cholesky row k of (G_active + eps*I), rsqrtf-based
    float ss = gdiag + DEPSF;
#pragma unroll
    for (int j = 0; j < k; ++j) {
      float w = arowf[j];
#pragma unroll
      for (int tt = 0; tt < j; ++tt) w -= L[k][tt] * L[j][tt];
      w *= inv_d[j];
      L[k][j] = w;
      ss -= w * w;
    }
    const float inv = rsqrtf(ss);
    L[k][k]  = ss * inv;                    // = sqrt(ss)
    inv_d[k] = inv;

    // forward substitution: only y[k] is new (y[0..k-1] unchanged)
    {
      float s2 = rhsf[k];
#pragma unroll
      for (int j = 0; j < k; ++j) s2 -= L[k][j] * y[j];
      y[k] = s2 * inv;
    }
    // backward substitution (full, sol changes every round)
#pragma unroll
    for (int i = k; i >= 0; --i) {
      float s2 = y[i];
#pragma unroll
      for (int j = i + 1; j <= k; ++j) s2 -= L[j][i] * sol[j];
      sol[i] = s2 * inv_d[i];
    }
  }

  // ---- epilogue: scatter the 5 coefficients (out pre-zeroed by memset)
  if (lane == 0) {
#pragma unroll
    for (int s = 0; s < NSPARSE; ++s)
      out[(size_t)idxs[s] * BATCH + cglob] = sol[s];
  }
}

// ---------------------------------------------------------------------------
extern "C" void kernel_launch(void* const* d_in, const int* in_sizes, int n_in,
                              void* d_out, int out_size, void* d_ws,
                              size_t ws_size, hipStream_t stream) {
  (void)in_sizes; (void)n_in; (void)out_size; (void)ws_size;
  const float* X = (const float*)d_in[0];   // (64, 65536)
  const float* D = (const float*)d_in[1];   // (64, 512)
  float* out = (float*)d_out;               // (512, 65536)
  float* gram = (float*)d_ws;               // 1 MB scratch

  ksvd_prep<<<(NATOMS * NATOMS) / 256, 256, 0, stream>>>(D, gram);
  hipMemsetAsync(out, 0, (size_t)NATOMS * BATCH * sizeof(float), stream);
  ksvd_main<<<BATCH / BT, 256, 0, stream>>>(X, D, gram, out);
}